// Round 14
// baseline (62.214 us; speedup 1.0000x reference)
//
#include <hip/hip_runtime.h>
#include <math.h>

#define T_LEN    20000
#define NBC      1280      // 32*40 sequences, one block each
#define NTHREADS 256
#define CS       16        // elements per thread per round (16 = proven no-spill)
#define ACT      250       // active threads per round
#define TILE     (ACT*CS)  // 4000 elements per round
#define ROUNDS   5         // 5*4000 = 20000

// Immediate permeability:
//   ppi = (p3/p1) * log1p(exp(p1*x)),  p1 = ln2*(PIMAX/PIREST) = 50*ln2
// Base-2 identity (valid for ALL x, branch-free):
//   ppi = 0.012 * log2(1 + 2^(50x)) = 0.012 * (50x + log2(1 + 2^(-50x)))
__device__ __forceinline__ float softplus_ppi(float x) {
    float y = 50.0f * x;
    float t = __builtin_exp2f(-y);        // v_exp_f32
    float l = __builtin_log2f(1.0f + t);  // v_log_f32
    return 0.012f * (y + l);
}

__global__ __launch_bounds__(NTHREADS, 5)   // 5 blocks/CU -> all 1280 resident
void na_scan_kernel(const float* __restrict__ ihcl, float* __restrict__ out) {
    const int bc   = blockIdx.x;
    const int tid  = threadIdx.x;
    const int lane = tid & 63;
    const int wv   = tid >> 6;             // wave id 0..3
    const long base = (long)bc * T_LEN;

    // reference constants: a_i = 0.1, a_l = 0.01
    const float A_I = 0.1f;
    const float A_L = 0.01f;
    const float PLc = 0.06f;
    const float PGc = 0.03f;
    const float BE  = 0.1f  * PLc;                 // 0.006
    const float GA  = 0.01f * PLc;                 // 0.0006
    const float DE  = 1.0f - 0.01f * (0.06f + 0.03f);  // 0.9991
    const float CI0 = 4166.666666666667f;          // SPONT/PIREST
    const float CL0 = 5000.0f;
    const float CG  = 6666.6669921875f;            // f32-exact per reference
    const float CLC = 0.01f * 0.03f * CG;

    __shared__ float wt[4][6];   // per-wave tile-total maps (m00,m01,m10,m11,v0,v1)

    float CIr = CI0, CLr = CL0;            // running state entering current round
    const bool active = (tid < ACT);
    const float4* srcb = reinterpret_cast<const float4*>(ihcl + base);

    // prologue: prefetch round 0's inputs
    float4 qa, qb, qc, qd;
    if (active) {
        const float4* s = srcb + (tid * CS) / 4;
        qa = s[0]; qb = s[1]; qc = s[2]; qd = s[3];
    }

    #pragma unroll 1
    for (int r = 0; r < ROUNDS; ++r) {
        const int t0 = r * TILE + tid * CS;

        // ---- pass 1: softplus + compose this chunk's affine map; keep ppi in regs ----
        float ppi_[CS];
        float m00 = 1.f, m01 = 0.f, m10 = 0.f, m11 = 1.f, v0 = 0.f, v1 = 0.f;

        if (active) {
            float xs[CS] = {qa.x,qa.y,qa.z,qa.w, qb.x,qb.y,qb.z,qb.w,
                            qc.x,qc.y,qc.z,qc.w, qd.x,qd.y,qd.z,qd.w};
            #pragma unroll
            for (int e = 0; e < CS; ++e) {
                float ppi = softplus_ppi(xs[e]);
                ppi_[e] = ppi;
                bool skip = (e == 0) && (r == 0) && (tid == 0);  // global t=0: identity
                if (!skip) {
                    float al = 1.0f - A_I * (ppi + PLc);
                    // A = [[al, BE], [GA*al, GA*BE + DE]], b = (0, CLC)
                    float nm00 = al * m00 + BE * m10;
                    float nm01 = al * m01 + BE * m11;
                    float nv0  = al * v0  + BE * v1;
                    m10 = GA * nm00 + DE * m10;
                    m11 = GA * nm01 + DE * m11;
                    v1  = GA * nv0  + DE * v1 + CLC;
                    m00 = nm00; m01 = nm01; v0 = nv0;
                }
            }
        }

        // ---- prefetch next round's inputs; latency hides under scan + replay ----
        if (active && (r + 1 < ROUNDS)) {
            const float4* s = srcb + ((r + 1) * TILE + tid * CS) / 4;
            qa = s[0]; qb = s[1]; qc = s[2]; qd = s[3];
        }

        // ---- wave-level inclusive scan of affine maps (register-only, no barriers) ----
        #pragma unroll
        for (int d = 1; d < 64; d <<= 1) {
            float a00 = __shfl_up(m00, d);
            float a01 = __shfl_up(m01, d);
            float a10 = __shfl_up(m10, d);
            float a11 = __shfl_up(m11, d);
            float av0 = __shfl_up(v0,  d);
            float av1 = __shfl_up(v1,  d);
            if (lane >= d) {
                // mine after left: M = M_mine*M_left ; v = M_mine*v_left + v_mine
                float r00 = m00*a00 + m01*a10;
                float r01 = m00*a01 + m01*a11;
                float r10 = m10*a00 + m11*a10;
                float r11 = m10*a01 + m11*a11;
                float rv0 = m00*av0 + m01*av1 + v0;
                float rv1 = m10*av0 + m11*av1 + v1;
                m00=r00; m01=r01; m10=r10; m11=r11; v0=rv0; v1=rv1;
            }
        }

        // ---- cross-wave exchange: lane 63 publishes wave total ----
        if (lane == 63) {
            wt[wv][0]=m00; wt[wv][1]=m01; wt[wv][2]=m10;
            wt[wv][3]=m11; wt[wv][4]=v0;  wt[wv][5]=v1;
        }
        __syncthreads();

        // exclusive in-wave prefix (shift inclusive by one lane)
        float e00 = __shfl_up(m00, 1), e01 = __shfl_up(m01, 1);
        float e10 = __shfl_up(m10, 1), e11 = __shfl_up(m11, 1);
        float ev0 = __shfl_up(v0,  1), ev1 = __shfl_up(v1,  1);

        // start state of my chunk: apply preceding waves' totals, then my
        // in-wave exclusive map — matrix*VECTOR applies only.
        float CIs = CIr, CLs = CLr;
        for (int ww = 0; ww < wv; ++ww) {
            float a = CIs;
            CIs = wt[ww][0]*a + wt[ww][1]*CLs + wt[ww][4];
            CLs = wt[ww][2]*a + wt[ww][3]*CLs + wt[ww][5];
        }
        if (lane > 0) {
            float a = CIs;
            CIs = e00*a + e01*CLs + ev0;
            CLs = e10*a + e11*CLs + ev1;
        }

        // running state for next round: all 4 wave totals applied in order
        float nCI = CIr, nCL = CLr;
        #pragma unroll
        for (int ww = 0; ww < 4; ++ww) {
            float a = nCI;
            nCI = wt[ww][0]*a + wt[ww][1]*nCL + wt[ww][4];
            nCL = wt[ww][2]*a + wt[ww][3]*nCL + wt[ww][5];
        }

        // ---- replay chunk with exact reference update, write output ----
        if (active) {
            float CI = CIs, CL = CLs;
            float4* dst = reinterpret_cast<float4*>(out + base + t0);
            #pragma unroll
            for (int j = 0; j < CS / 4; ++j) {
                float os[4];
                #pragma unroll
                for (int q = 0; q < 4; ++q) {
                    const int e = j * 4 + q;
                    if (e == 0 && r == 0 && tid == 0) { os[q] = 50.0f; continue; }
                    float ppi = ppi_[e];
                    CI = CI + A_I * (-ppi * CI + PLc * (CL - CI));
                    CL = CL + A_L * (-PLc * (CL - CI) + PGc * (CG - CL));
                    os[q] = CI * ppi;
                }
                dst[j] = make_float4(os[0], os[1], os[2], os[3]);
            }
        }

        CIr = nCI; CLr = nCL;
        __syncthreads();   // protect wt[] before next round's lane-63 writes
    }
}

extern "C" void kernel_launch(void* const* d_in, const int* in_sizes, int n_in,
                              void* d_out, int out_size, void* d_ws, size_t ws_size,
                              hipStream_t stream) {
    const float* ihcl = (const float*)d_in[0];
    float* out = (float*)d_out;
    na_scan_kernel<<<NBC, NTHREADS, 0, stream>>>(ihcl, out);
}

// Round 15
// 60.157 us; speedup vs baseline: 1.0342x; 1.0342x over previous
//
#include <hip/hip_runtime.h>
#include <math.h>

#define T_LEN    20000
#define NBC      1280      // 32*40 sequences, one block each
#define NTHREADS 256
#define CS       16        // elements per thread per round (16 = max register array; >16 -> scratch)
#define ACT      250       // active threads per round
#define TILE     (ACT*CS)  // 4000 elements per round
#define ROUNDS   5         // 5*4000 = 20000

// Immediate permeability:
//   ppi = (p3/p1) * log1p(exp(p1*x)),  p1 = ln2*(PIMAX/PIREST) = 50*ln2
// Base-2 identity (valid for ALL x, branch-free):
//   ppi = 0.012 * log2(1 + 2^(50x)) = 0.012 * (50x + log2(1 + 2^(-50x)))
__device__ __forceinline__ float softplus_ppi(float x) {
    float y = 50.0f * x;
    float t = __builtin_exp2f(-y);        // v_exp_f32
    float l = __builtin_log2f(1.0f + t);  // v_log_f32
    return 0.012f * (y + l);
}

__global__ __launch_bounds__(NTHREADS, 5)   // 5 blocks/CU -> all 1280 resident
void na_scan_kernel(const float* __restrict__ ihcl, float* __restrict__ out) {
    const int bc   = blockIdx.x;
    const int tid  = threadIdx.x;
    const int lane = tid & 63;
    const int wv   = tid >> 6;             // wave id 0..3
    const long base = (long)bc * T_LEN;

    // reference constants: a_i = 0.1, a_l = 0.01
    const float A_I = 0.1f;
    const float A_L = 0.01f;
    const float PLc = 0.06f;
    const float PGc = 0.03f;
    const float BE  = 0.1f  * PLc;                 // 0.006
    const float GA  = 0.01f * PLc;                 // 0.0006
    const float DE  = 1.0f - 0.01f * (0.06f + 0.03f);  // 0.9991
    const float CI0 = 4166.666666666667f;          // SPONT/PIREST
    const float CL0 = 5000.0f;
    const float CG  = 6666.6669921875f;            // f32-exact per reference
    const float CLC = 0.01f * 0.03f * CG;

    // double-buffered per-wave tile-total maps -> ONE barrier per round.
    // WAR safety: round r+2's write to wt[r&1] occurs after barrier(r+1),
    // which every round-r reader has already passed.
    __shared__ float wt[2][4][6];

    float CIr = CI0, CLr = CL0;            // running state entering current round
    const bool active = (tid < ACT);

    #pragma unroll 1
    for (int r = 0; r < ROUNDS; ++r) {
        const int t0 = r * TILE + tid * CS;
        const int buf = r & 1;

        // ---- pass 1: softplus + compose this chunk's affine map; keep ppi in regs ----
        float ppi_[CS];
        float m00 = 1.f, m01 = 0.f, m10 = 0.f, m11 = 1.f, v0 = 0.f, v1 = 0.f;

        if (active) {
            const float4* src = reinterpret_cast<const float4*>(ihcl + base + t0);
            #pragma unroll
            for (int j = 0; j < CS / 4; ++j) {
                float4 q = src[j];
                float xs[4] = {q.x, q.y, q.z, q.w};
                #pragma unroll
                for (int qq = 0; qq < 4; ++qq) {
                    const int e = j * 4 + qq;
                    float ppi = softplus_ppi(xs[qq]);
                    ppi_[e] = ppi;
                    bool skip = (e == 0) && (r == 0) && (tid == 0);  // global t=0: identity
                    if (!skip) {
                        float al = 1.0f - A_I * (ppi + PLc);
                        // A = [[al, BE], [GA*al, GA*BE + DE]], b = (0, CLC)
                        float nm00 = al * m00 + BE * m10;
                        float nm01 = al * m01 + BE * m11;
                        float nv0  = al * v0  + BE * v1;
                        m10 = GA * nm00 + DE * m10;
                        m11 = GA * nm01 + DE * m11;
                        v1  = GA * nv0  + DE * v1 + CLC;
                        m00 = nm00; m01 = nm01; v0 = nv0;
                    }
                }
            }
        }

        // ---- wave-level inclusive scan of affine maps (register-only, no barriers) ----
        #pragma unroll
        for (int d = 1; d < 64; d <<= 1) {
            float a00 = __shfl_up(m00, d);
            float a01 = __shfl_up(m01, d);
            float a10 = __shfl_up(m10, d);
            float a11 = __shfl_up(m11, d);
            float av0 = __shfl_up(v0,  d);
            float av1 = __shfl_up(v1,  d);
            if (lane >= d) {
                // mine after left: M = M_mine*M_left ; v = M_mine*v_left + v_mine
                float r00 = m00*a00 + m01*a10;
                float r01 = m00*a01 + m01*a11;
                float r10 = m10*a00 + m11*a10;
                float r11 = m10*a01 + m11*a11;
                float rv0 = m00*av0 + m01*av1 + v0;
                float rv1 = m10*av0 + m11*av1 + v1;
                m00=r00; m01=r01; m10=r10; m11=r11; v0=rv0; v1=rv1;
            }
        }

        // ---- cross-wave exchange: lane 63 publishes wave total ----
        if (lane == 63) {
            wt[buf][wv][0]=m00; wt[buf][wv][1]=m01; wt[buf][wv][2]=m10;
            wt[buf][wv][3]=m11; wt[buf][wv][4]=v0;  wt[buf][wv][5]=v1;
        }
        __syncthreads();   // the ONLY barrier this round

        // exclusive in-wave prefix (shift inclusive by one lane)
        float e00 = __shfl_up(m00, 1), e01 = __shfl_up(m01, 1);
        float e10 = __shfl_up(m10, 1), e11 = __shfl_up(m11, 1);
        float ev0 = __shfl_up(v0,  1), ev1 = __shfl_up(v1,  1);

        // start state of my chunk: apply preceding waves' totals, then my
        // in-wave exclusive map — matrix*VECTOR applies only.
        float CIs = CIr, CLs = CLr;
        for (int ww = 0; ww < wv; ++ww) {
            float a = CIs;
            CIs = wt[buf][ww][0]*a + wt[buf][ww][1]*CLs + wt[buf][ww][4];
            CLs = wt[buf][ww][2]*a + wt[buf][ww][3]*CLs + wt[buf][ww][5];
        }
        if (lane > 0) {
            float a = CIs;
            CIs = e00*a + e01*CLs + ev0;
            CLs = e10*a + e11*CLs + ev1;
        }

        // running state for next round: all 4 wave totals applied in order
        float nCI = CIr, nCL = CLr;
        #pragma unroll
        for (int ww = 0; ww < 4; ++ww) {
            float a = nCI;
            nCI = wt[buf][ww][0]*a + wt[buf][ww][1]*nCL + wt[buf][ww][4];
            nCL = wt[buf][ww][2]*a + wt[buf][ww][3]*nCL + wt[buf][ww][5];
        }

        // ---- replay chunk with exact reference update, write output ----
        if (active) {
            float CI = CIs, CL = CLs;
            float4* dst = reinterpret_cast<float4*>(out + base + t0);
            #pragma unroll
            for (int j = 0; j < CS / 4; ++j) {
                float os[4];
                #pragma unroll
                for (int q = 0; q < 4; ++q) {
                    const int e = j * 4 + q;
                    if (e == 0 && r == 0 && tid == 0) { os[q] = 50.0f; continue; }
                    float ppi = ppi_[e];
                    CI = CI + A_I * (-ppi * CI + PLc * (CL - CI));
                    CL = CL + A_L * (-PLc * (CL - CI) + PGc * (CG - CL));
                    os[q] = CI * ppi;
                }
                dst[j] = make_float4(os[0], os[1], os[2], os[3]);
            }
        }

        CIr = nCI; CLr = nCL;
        // no end-of-round barrier: wt is double-buffered
    }
}

extern "C" void kernel_launch(void* const* d_in, const int* in_sizes, int n_in,
                              void* d_out, int out_size, void* d_ws, size_t ws_size,
                              hipStream_t stream) {
    const float* ihcl = (const float*)d_in[0];
    float* out = (float*)d_out;
    na_scan_kernel<<<NBC, NTHREADS, 0, stream>>>(ihcl, out);
}